// Round 1
// baseline (281.182 us; speedup 1.0000x reference)
//
#include <hip/hip_runtime.h>

// CQT on gfx950.
// Math: fold kr/ki through the DFT kernels -> combined time-domain kernels
//   Wr[b,n] = sum_k kr[b,k]*wcos[k,n] - ki[b,k]*wsin[k,n]
//   Wi[b,n] = sum_k kr[b,k]*wsin[k,n] + ki[b,k]*wcos[k,n]
//   cqt[b,f] = sqrt( (sum_n x[512f+n]*Wr[b,n])^2 + (sum_n x[512f+n]*Wi[b,n])^2 )
// Kernel 1 (fp32 VALU): W prep, interleaved rows [2b]=Wr,[2b+1]=Wi, padded to 192 rows, bf16 in d_ws.
// Kernel 2 (bf16 MFMA 16x16x32): C[192,16384] = W @ B with B[k,f] = x[512f+k] built on the fly.

#define HOPS 512
#define NBINS 84
#define FREQB 1025
#define FFTLEN 2048
#define NFRAMES 16381
#define MROWS 192

typedef short bf16x8 __attribute__((ext_vector_type(8)));
typedef float f32x4 __attribute__((ext_vector_type(4)));

__device__ __forceinline__ unsigned short f32_to_bf16(float f) {
    union { float f; unsigned u; } v; v.f = f;
    return (unsigned short)((v.u + 0x7FFFu + ((v.u >> 16) & 1u)) >> 16);
}

// ---------------- Kernel 1: W prep (fp32 VALU) ----------------
// grid 256 blocks x 256 thr. Block owns 8 n-columns (XCD-swizzled), all 96 (padded) bins.
// t: n = t&7, g = t>>3 (0..31); b = 32j+g, j=0..2. Rows b>=84 staged as zeros.
__global__ __launch_bounds__(256) void wprep_kernel(
    const float* __restrict__ wcos, const float* __restrict__ wsin,
    const float* __restrict__ kr,   const float* __restrict__ ki,
    unsigned short* __restrict__ Wp)
{
    __shared__ __align__(16) float wc0[8][68];   // [n][k] wcos chunk
    __shared__ __align__(16) float wc1[8][68];   // [n][k] wsin chunk
    __shared__ __align__(16) float krl[96][68];  // [b][k]
    __shared__ __align__(16) float kil[96][68];

    const int t = threadIdx.x;
    const int bid = blockIdx.x;
    // XCD-aware swizzle: blocks resident on one XCD cover contiguous n (L2 line reuse
    // for the 8-column strided wcos/wsin reads).
    const int n0 = (((bid & 7) * 32) + (bid >> 3)) * 8;
    const int n = t & 7;
    const int g = t >> 3;

    float accr[3] = {0.f, 0.f, 0.f};
    float acci[3] = {0.f, 0.f, 0.f};

    for (int k0 = 0; k0 < FREQB; k0 += 64) {
        const int kc = (FREQB - k0) < 64 ? (FREQB - k0) : 64;
        // stage wcos/wsin [64k x 8n] transposed -> [n][k], zero-pad k>=kc
        #pragma unroll
        for (int p = 0; p < 4; ++p) {
            int e  = t + p * 256;         // 0..1023
            int mk = e & 63;
            int mn = (e >> 6) & 7;
            int mm = e >> 9;              // 0:wcos 1:wsin
            float v = 0.f;
            if (mk < kc) v = (mm ? wsin : wcos)[(k0 + mk) * FFTLEN + n0 + mn];
            float (*dst)[68] = mm ? wc1 : wc0;
            dst[mn][mk] = v;
        }
        // stage kr/ki [96 x 64], rows >=84 and k>=kc zeroed
        #pragma unroll
        for (int p = 0; p < 24; ++p) {
            int e = t + p * 256;          // 0..6143
            int b = e >> 6;               // 0..95
            int kk = e & 63;
            float vr = 0.f, vi = 0.f;
            if (b < NBINS && kk < kc) {
                vr = kr[b * FREQB + k0 + kk];
                vi = ki[b * FREQB + k0 + kk];
            }
            krl[b][kk] = vr;
            kil[b][kk] = vi;
        }
        __syncthreads();

        #pragma unroll
        for (int kq = 0; kq < 16; ++kq) {
            float4 c = *(const float4*)&wc0[n][kq * 4];
            float4 s = *(const float4*)&wc1[n][kq * 4];
            #pragma unroll
            for (int j = 0; j < 3; ++j) {
                int b = 32 * j + g;
                float4 r4 = *(const float4*)&krl[b][kq * 4];
                float4 i4 = *(const float4*)&kil[b][kq * 4];
                float ar = accr[j], ai = acci[j];
                ar += r4.x * c.x; ar -= i4.x * s.x;
                ar += r4.y * c.y; ar -= i4.y * s.y;
                ar += r4.z * c.z; ar -= i4.z * s.z;
                ar += r4.w * c.w; ar -= i4.w * s.w;
                ai += r4.x * s.x; ai += i4.x * c.x;
                ai += r4.y * s.y; ai += i4.y * c.y;
                ai += r4.z * s.z; ai += i4.z * c.z;
                ai += r4.w * s.w; ai += i4.w * c.w;
                accr[j] = ar; acci[j] = ai;
            }
        }
        __syncthreads();
    }

    #pragma unroll
    for (int j = 0; j < 3; ++j) {
        int b = 32 * j + g;  // 0..95; b>=84 accumulated zeros -> zero-pads rows 168..191
        Wp[(2 * b)     * FFTLEN + n0 + n] = f32_to_bf16(accr[j]);
        Wp[(2 * b + 1) * FFTLEN + n0 + n] = f32_to_bf16(acci[j]);
    }
}

// ---------------- Kernel 2: main GEMM (bf16 MFMA) ----------------
// grid 256 blocks x 256 thr (4 waves). Block tile: 192 rows x 64 frames, BK=64.
// wave w: m-group = w>>1 (96 rows = 6 m-tiles), f-group = w&1 (32 f = 2 n-subtiles).
__global__ __launch_bounds__(256) void cqt_kernel(
    const float* __restrict__ x, const unsigned short* __restrict__ Wp,
    float* __restrict__ out)
{
    __shared__ __align__(16) unsigned short Al[MROWS * 72]; // [row][k], stride 72 (2-way bank alias = free)
    __shared__ __align__(16) unsigned short Bl[64 * 72];    // [f][k], stride 72

    const int t  = threadIdx.x;
    const int f0 = blockIdx.x * 64;
    const int w  = t >> 6;
    const int l  = t & 63;
    const int mg = w >> 1;
    const int fg = w & 1;
    const int q  = l >> 4;
    const int col = l & 15;

    f32x4 acc[6][2];
    #pragma unroll
    for (int mt = 0; mt < 6; ++mt)
        #pragma unroll
        for (int nt = 0; nt < 2; ++nt)
            acc[mt][nt] = (f32x4){0.f, 0.f, 0.f, 0.f};

    for (int k0 = 0; k0 < FFTLEN; k0 += 64) {
        // stage A: 192x64 bf16 = 1536 uint4
        #pragma unroll
        for (int p = 0; p < 6; ++p) {
            int e = t + p * 256;
            int row = e >> 3, oct = e & 7;
            uint4 v = *(const uint4*)(Wp + row * FFTLEN + k0 + oct * 8);
            *(uint4*)(Al + row * 72 + oct * 8) = v;
        }
        // stage B: B[f][k] = bf16(x[(f0+f)*512 + k0 + k]), 64x64 = 1024 float4
        #pragma unroll
        for (int p = 0; p < 4; ++p) {
            int e = t + p * 256;
            int f = e >> 4, qq = e & 15;
            int fi = f0 + f;
            float4 v = make_float4(0.f, 0.f, 0.f, 0.f);
            if (fi < NFRAMES) v = *(const float4*)(x + fi * HOPS + k0 + qq * 4);
            ushort4 bsv;
            bsv.x = f32_to_bf16(v.x); bsv.y = f32_to_bf16(v.y);
            bsv.z = f32_to_bf16(v.z); bsv.w = f32_to_bf16(v.w);
            *(ushort4*)(Bl + f * 72 + qq * 4) = bsv;
        }
        __syncthreads();

        #pragma unroll
        for (int ks = 0; ks < 2; ++ks) {
            bf16x8 bfrag[2], afrag[6];
            #pragma unroll
            for (int nt = 0; nt < 2; ++nt)
                bfrag[nt] = *(const bf16x8*)(Bl + (fg * 32 + nt * 16 + col) * 72 + ks * 32 + q * 8);
            #pragma unroll
            for (int mt = 0; mt < 6; ++mt)
                afrag[mt] = *(const bf16x8*)(Al + (mg * 96 + mt * 16 + col) * 72 + ks * 32 + q * 8);
            #pragma unroll
            for (int mt = 0; mt < 6; ++mt)
                #pragma unroll
                for (int nt = 0; nt < 2; ++nt)
                    acc[mt][nt] = __builtin_amdgcn_mfma_f32_16x16x32_bf16(
                        afrag[mt], bfrag[nt], acc[mt][nt], 0, 0, 0);
        }
        __syncthreads();
    }

    // epilogue: C/D layout col=lane&15, row=quad*4+reg. Row interleave puts (Wr,Wi)
    // for bin b0 in regs (x,y) and for bin b0+1 in regs (z,w) of the same lane.
    #pragma unroll
    for (int mt = 0; mt < 6; ++mt) {
        int row_base = mg * 96 + mt * 16 + 4 * q;
        int b0 = row_base >> 1;
        #pragma unroll
        for (int nt = 0; nt < 2; ++nt) {
            int f = f0 + fg * 32 + nt * 16 + col;
            if (f < NFRAMES) {
                f32x4 a = acc[mt][nt];
                if (b0 < NBINS)
                    out[b0 * NFRAMES + f] = sqrtf(a.x * a.x + a.y * a.y);
                if (b0 + 1 < NBINS)
                    out[(b0 + 1) * NFRAMES + f] = sqrtf(a.z * a.z + a.w * a.w);
            }
        }
    }
}

extern "C" void kernel_launch(void* const* d_in, const int* in_sizes, int n_in,
                              void* d_out, int out_size, void* d_ws, size_t ws_size,
                              hipStream_t stream) {
    const float* x    = (const float*)d_in[0];
    const float* wcos = (const float*)d_in[1];
    const float* wsin = (const float*)d_in[2];
    const float* kr   = (const float*)d_in[3];
    const float* ki   = (const float*)d_in[4];
    float* out = (float*)d_out;
    unsigned short* Wp = (unsigned short*)d_ws; // 192*2048*2 = 786432 B

    wprep_kernel<<<dim3(256), dim3(256), 0, stream>>>(wcos, wsin, kr, ki, Wp);
    cqt_kernel<<<dim3(256), dim3(256), 0, stream>>>(x, Wp, out);
}

// Round 2
// 184.707 us; speedup vs baseline: 1.5223x; 1.5223x over previous
//
#include <hip/hip_runtime.h>

// CQT on gfx950.
//   Wr[b,n] = sum_k kr[b,k]*cos(2pi k n/2048) - ki[b,k]*sin(...)
//   Wi[b,n] = sum_k kr[b,k]*sin(...) + ki[b,k]*cos(...)
//   cqt[b,f] = sqrt( (sum_n x[512f+n]*Wr[b,n])^2 + (sum_n x[512f+n]*Wi[b,n])^2 )
// K1 wprep: trig computed on the fly (kills 17MB uncoalesced wcos/wsin reads),
//           k-split S=8 -> fp32 partials in ws.  K2 wreduce: sum+cast to bf16 Wp.
// K3 cqt: bf16 MFMA GEMM C[192,16381] = Wp @ B, B[k,f]=x[512f+k], double-buffered
//         LDS, one barrier per K-iter.

#define HOPS 512
#define NBINS 84
#define FREQB 1025
#define FFTLEN 2048
#define NFRAMES 16381
#define MROWS 192
#define NSPLIT 8

typedef short bf16x8 __attribute__((ext_vector_type(8)));
typedef float f32x4 __attribute__((ext_vector_type(4)));

__device__ __forceinline__ unsigned short f32_to_bf16(float f) {
    union { float f; unsigned u; } v; v.f = f;
    return (unsigned short)((v.u + 0x7FFFu + ((v.u >> 16) & 1u)) >> 16);
}

// ---------------- Kernel 1: W prep (fp32 VALU, trig on the fly) ----------------
// grid 256 = 32 n-groups (64 cols) x 8 k-splits. 256 thr: g=t&15 -> bins g*6..+5,
// nthr=t>>4 -> cols nthr*4..+3. Writes fp32 partial[s][192][2048].
__global__ __launch_bounds__(256) void wprep_kernel(
    const float* __restrict__ kr, const float* __restrict__ ki,
    float* __restrict__ partial)
{
    __shared__ __align__(16) float trc[64][64];   // [col][k] cos (reads are broadcast)
    __shared__ __align__(16) float trs[64][64];   // [col][k] sin
    __shared__ __align__(16) float krl[96][68];   // [b][k], stride 68 -> 2-way (free)
    __shared__ __align__(16) float kil[96][68];

    const int t = threadIdx.x;
    const int g = t & 15;
    const int nthr = t >> 4;
    const int s = blockIdx.x >> 5;
    const int ng = blockIdx.x & 31;
    const int n0 = ng * 64;
    const int kstart = s * 128;
    const int kend = (s == NSPLIT - 1) ? FREQB : (kstart + 128);

    float2 acc[6][4];
    #pragma unroll
    for (int j = 0; j < 6; ++j)
        #pragma unroll
        for (int cc = 0; cc < 4; ++cc)
            acc[j][cc] = make_float2(0.f, 0.f);

    for (int k0 = kstart; k0 < kend; k0 += 64) {
        const int kc = (kend - k0) < 64 ? (kend - k0) : 64;
        // trig staging: 64 cols x 64 k x {cos,sin} = 8192 values
        #pragma unroll
        for (int p = 0; p < 32; ++p) {
            int e = t + p * 256;
            int which = e >> 12;          // 0: cos, 1: sin (wave-uniform)
            int r = e & 4095;
            int col = r >> 6;
            int kk = r & 63;
            float v = 0.f;
            if (kk < kc) {
                int prod = ((k0 + kk) * (n0 + col)) & (FFTLEN - 1);
                float ang = (float)prod * 0.00306796157577128f; // 2*pi/2048
                v = which ? __sinf(ang) : __cosf(ang);
            }
            if (which) trs[col][kk] = v; else trc[col][kk] = v;
        }
        // kr/ki staging: 96 x 64, coalesced float4; zeros for b>=84 / k>=kc
        #pragma unroll
        for (int p = 0; p < 6; ++p) {
            int e = t + p * 256;          // < 1536
            int b = e >> 4;
            int kk4 = (e & 15) * 4;
            float4 vr = make_float4(0.f, 0.f, 0.f, 0.f);
            float4 vi = make_float4(0.f, 0.f, 0.f, 0.f);
            if (b < NBINS) {
                if (kk4 + 4 <= kc) {
                    vr = *(const float4*)(kr + b * FREQB + k0 + kk4);
                    vi = *(const float4*)(ki + b * FREQB + k0 + kk4);
                } else {
                    float r4[4], i4[4];
                    #pragma unroll
                    for (int i = 0; i < 4; ++i) {
                        int kkk = kk4 + i;
                        bool ok = kkk < kc;
                        r4[i] = ok ? kr[b * FREQB + k0 + kkk] : 0.f;
                        i4[i] = ok ? ki[b * FREQB + k0 + kkk] : 0.f;
                    }
                    vr = make_float4(r4[0], r4[1], r4[2], r4[3]);
                    vi = make_float4(i4[0], i4[1], i4[2], i4[3]);
                }
            }
            *(float4*)&krl[b][kk4] = vr;
            *(float4*)&kil[b][kk4] = vi;
        }
        __syncthreads();

        const int nkq = (kc + 3) >> 2;
        for (int kq = 0; kq < nkq; ++kq) {
            float4 kr4[6], ki4[6];
            #pragma unroll
            for (int j = 0; j < 6; ++j) {
                kr4[j] = *(const float4*)&krl[g * 6 + j][kq * 4];
                ki4[j] = *(const float4*)&kil[g * 6 + j][kq * 4];
            }
            #pragma unroll
            for (int cc = 0; cc < 4; ++cc) {
                int col = nthr * 4 + cc;
                float4 c4 = *(const float4*)&trc[col][kq * 4];
                float4 s4 = *(const float4*)&trs[col][kq * 4];
                #pragma unroll
                for (int j = 0; j < 6; ++j) {
                    float ar = acc[j][cc].x, ai = acc[j][cc].y;
                    ar += kr4[j].x * c4.x; ar -= ki4[j].x * s4.x;
                    ar += kr4[j].y * c4.y; ar -= ki4[j].y * s4.y;
                    ar += kr4[j].z * c4.z; ar -= ki4[j].z * s4.z;
                    ar += kr4[j].w * c4.w; ar -= ki4[j].w * s4.w;
                    ai += kr4[j].x * s4.x; ai += ki4[j].x * c4.x;
                    ai += kr4[j].y * s4.y; ai += ki4[j].y * c4.y;
                    ai += kr4[j].z * s4.z; ai += ki4[j].z * c4.z;
                    ai += kr4[j].w * s4.w; ai += ki4[j].w * c4.w;
                    acc[j][cc] = make_float2(ar, ai);
                }
            }
        }
        __syncthreads();
    }

    // write partial[s]: rows 2b=Wr, 2b+1=Wi; wave covers one 64B line per row
    float* base = partial + (size_t)s * (MROWS * FFTLEN) + n0 + nthr * 4;
    #pragma unroll
    for (int j = 0; j < 6; ++j) {
        int b = g * 6 + j;  // 0..95, b>=84 are zeros -> zero-pad rows 168..191
        float4 vr = make_float4(acc[j][0].x, acc[j][1].x, acc[j][2].x, acc[j][3].x);
        float4 vi = make_float4(acc[j][0].y, acc[j][1].y, acc[j][2].y, acc[j][3].y);
        *(float4*)(base + (2 * b) * FFTLEN) = vr;
        *(float4*)(base + (2 * b + 1) * FFTLEN) = vi;
    }
}

// ---------------- Kernel 2: reduce partials + cast to bf16 ----------------
// grid 384 x 256: each thread one float4 of the 192x2048 result.
__global__ __launch_bounds__(256) void wreduce_kernel(
    const float* __restrict__ partial, unsigned short* __restrict__ Wp)
{
    int gid = blockIdx.x * 256 + threadIdx.x;   // < 98304
    const float4* p4 = (const float4*)partial;
    float4 sum = p4[gid];
    #pragma unroll
    for (int s = 1; s < NSPLIT; ++s) {
        float4 v = p4[(size_t)s * 98304 + gid];
        sum.x += v.x; sum.y += v.y; sum.z += v.z; sum.w += v.w;
    }
    ushort4 o;
    o.x = f32_to_bf16(sum.x); o.y = f32_to_bf16(sum.y);
    o.z = f32_to_bf16(sum.z); o.w = f32_to_bf16(sum.w);
    ((ushort4*)Wp)[gid] = o;
}

// ---------------- Kernel 3: main GEMM (bf16 MFMA, dbuf, 1 barrier/iter) ------
__global__ __launch_bounds__(256) void cqt_kernel(
    const float* __restrict__ x, const unsigned short* __restrict__ Wp,
    float* __restrict__ out)
{
    __shared__ __align__(16) unsigned short Al[2][MROWS * 72];
    __shared__ __align__(16) unsigned short Bl[2][64 * 72];

    const int t  = threadIdx.x;
    const int f0 = blockIdx.x * 64;
    const int w  = t >> 6;
    const int l  = t & 63;
    const int mg = w >> 1;
    const int fg = w & 1;
    const int q  = l >> 4;
    const int col = l & 15;

    f32x4 acc[6][2];
    #pragma unroll
    for (int mt = 0; mt < 6; ++mt)
        #pragma unroll
        for (int nt = 0; nt < 2; ++nt)
            acc[mt][nt] = (f32x4){0.f, 0.f, 0.f, 0.f};

    uint4 aR[6];
    float4 bR[4];

    auto load_chunk = [&](int kidx) {
        int k0 = kidx * 64;
        #pragma unroll
        for (int p = 0; p < 6; ++p) {
            int e = t + p * 256;
            int row = e >> 3, oct = e & 7;
            aR[p] = *(const uint4*)(Wp + row * FFTLEN + k0 + oct * 8);
        }
        #pragma unroll
        for (int p = 0; p < 4; ++p) {
            int e = t + p * 256;
            int f = e >> 4, qq = e & 15;
            int fi = f0 + f;
            bR[p] = (fi < NFRAMES) ? *(const float4*)(x + fi * HOPS + k0 + qq * 4)
                                   : make_float4(0.f, 0.f, 0.f, 0.f);
        }
    };
    auto write_lds = [&](int buf) {
        #pragma unroll
        for (int p = 0; p < 6; ++p) {
            int e = t + p * 256;
            int row = e >> 3, oct = e & 7;
            *(uint4*)(&Al[buf][row * 72 + oct * 8]) = aR[p];
        }
        #pragma unroll
        for (int p = 0; p < 4; ++p) {
            int e = t + p * 256;
            int f = e >> 4, qq = e & 15;
            ushort4 bv;
            bv.x = f32_to_bf16(bR[p].x); bv.y = f32_to_bf16(bR[p].y);
            bv.z = f32_to_bf16(bR[p].z); bv.w = f32_to_bf16(bR[p].w);
            *(ushort4*)(&Bl[buf][f * 72 + qq * 4]) = bv;
        }
    };
    auto compute = [&](int buf) {
        #pragma unroll
        for (int ks = 0; ks < 2; ++ks) {
            bf16x8 bfrag[2], afrag[6];
            #pragma unroll
            for (int nt = 0; nt < 2; ++nt)
                bfrag[nt] = *(const bf16x8*)(&Bl[buf][(fg * 32 + nt * 16 + col) * 72 + ks * 32 + q * 8]);
            #pragma unroll
            for (int mt = 0; mt < 6; ++mt)
                afrag[mt] = *(const bf16x8*)(&Al[buf][(mg * 96 + mt * 16 + col) * 72 + ks * 32 + q * 8]);
            #pragma unroll
            for (int mt = 0; mt < 6; ++mt)
                #pragma unroll
                for (int nt = 0; nt < 2; ++nt)
                    acc[mt][nt] = __builtin_amdgcn_mfma_f32_16x16x32_bf16(
                        afrag[mt], bfrag[nt], acc[mt][nt], 0, 0, 0);
        }
    };

    load_chunk(0);
    write_lds(0);
    __syncthreads();
    load_chunk(1);

    for (int it = 0; it < 32; ++it) {
        compute(it & 1);
        if (it < 31) {
            write_lds((it + 1) & 1);   // regs hold chunk it+1 (loads had whole compute to land)
            if (it < 30) load_chunk(it + 2);
            __syncthreads();
        }
    }

    // epilogue: C/D layout col=lane&15, row=quad*4+reg. Row interleave puts (Wr,Wi)
    // for bin b0 in regs (x,y) and bin b0+1 in regs (z,w) of the same lane.
    #pragma unroll
    for (int mt = 0; mt < 6; ++mt) {
        int row_base = mg * 96 + mt * 16 + 4 * q;
        int b0 = row_base >> 1;
        #pragma unroll
        for (int nt = 0; nt < 2; ++nt) {
            int f = f0 + fg * 32 + nt * 16 + col;
            if (f < NFRAMES) {
                f32x4 a = acc[mt][nt];
                if (b0 < NBINS)
                    out[b0 * NFRAMES + f] = sqrtf(a.x * a.x + a.y * a.y);
                if (b0 + 1 < NBINS)
                    out[(b0 + 1) * NFRAMES + f] = sqrtf(a.z * a.z + a.w * a.w);
            }
        }
    }
}

extern "C" void kernel_launch(void* const* d_in, const int* in_sizes, int n_in,
                              void* d_out, int out_size, void* d_ws, size_t ws_size,
                              hipStream_t stream) {
    const float* x    = (const float*)d_in[0];
    // d_in[1] (wcos) / d_in[2] (wsin) unused: trig computed on the fly
    const float* kr   = (const float*)d_in[3];
    const float* ki   = (const float*)d_in[4];
    float* out = (float*)d_out;

    unsigned short* Wp = (unsigned short*)d_ws;                      // 786,432 B
    float* partial = (float*)((char*)d_ws + 786432);                 // 12,582,912 B

    wprep_kernel<<<dim3(256), dim3(256), 0, stream>>>(kr, ki, partial);
    wreduce_kernel<<<dim3(384), dim3(256), 0, stream>>>(partial, Wp);
    cqt_kernel<<<dim3(256), dim3(256), 0, stream>>>(x, Wp, out);
}